// Round 6
// baseline (112.295 us; speedup 1.0000x reference)
//
#include <hip/hip_runtime.h>
#include <math.h>

// Problem: M=256 positives, 3M=768 negatives, NUM_GT=32,
// proto (4,128,128), maps (*,64,64), gt_masks (32,512,512).
//
// Mask-loss restructure (verified exact rounds 1-4):
//   mean(bce_m) = (1/512^2) * [ 16 * sum_{hw in 128^2} softplus(L_m[hw])
//                               - dot(coef_m, T[gt_m]) ]
//   T[g,p] = sum_{512^2} gt_masks[g] * proto[p, y/4, x/4]
//
// Structure (round 4, proven): 2 dispatches, ZERO device-scope atomics.
// Lesson from rounds 2-3: 256+ far-atomics to one line across 8 XCDs
// serialize at ~100ns each (~25 us) — never funnel block results through
// a single atomic scalar; use disjoint plain stores + a dependent kernel.
//
//   k_workers (640 blocks): [0,512) tmat slab partials -> Tpart;
//                           [512,640) softplus, 2 m's per block -> SP.
//   k_final   (1 block): reduce Tpart, cls+loc+combine, write scalar.
//
// NB: __builtin_nontemporal_load needs a clang ext_vector_type, not the
// HIP_vector_type float4 (round-5 compile fail).

#define INV_TOTAL (1.0f / (262144.0f * 256.0f))

typedef float floatx4 __attribute__((ext_vector_type(4)));

__device__ __forceinline__ float softplusf(float x) {
    return fmaxf(x, 0.0f) + __logf(1.0f + __expf(-fabsf(x)));
}

__device__ __forceinline__ float wave_sum(float v) {
    v += __shfl_down(v, 32);
    v += __shfl_down(v, 16);
    v += __shfl_down(v, 8);
    v += __shfl_down(v, 4);
    v += __shfl_down(v, 2);
    v += __shfl_down(v, 1);
    return v;
}

__global__ void __launch_bounds__(256)
k_workers(const float* __restrict__ proto,
          const float* __restrict__ map_coef,
          const float* __restrict__ gt_masks,
          const int* __restrict__ pos_idx,
          float* __restrict__ Tpart,   // [512*4] slab partials, slot = bid
          float* __restrict__ SP) {    // [256] per-m softplus sums
    const int bid = blockIdx.x;
    const int t = threadIdx.x;
    const int wave = t >> 6, lane = t & 63;
    __shared__ float smem[4][4];

    if (bid < 512) {
        // ---- tmat: partial T over a 32-row slab of gt_masks[g] ----
        const int g = bid >> 4, chunk = bid & 15;
        const float* mask = gt_masks + (size_t)g * (512 * 512);
        float tp0 = 0.f, tp1 = 0.f, tp2 = 0.f, tp3 = 0.f;
#pragma unroll 4
        for (int i = 0; i < 16; ++i) {
            int f = t + (i << 8);            // 0..4095 float4s in 32x512 slab
            int yl = f >> 7;                 // 128 float4 per row
            int k  = f & 127;
            int y  = (chunk << 5) + yl;
            // one-shot stream: non-temporal, don't evict proto from L2
            floatx4 mv = __builtin_nontemporal_load(
                reinterpret_cast<const floatx4*>(mask + y * 512 + (k << 2)));
            float s = (mv.x + mv.y) + (mv.z + mv.w);
            int cell = ((y >> 2) << 7) + k;
            tp0 = fmaf(s, proto[cell],         tp0);
            tp1 = fmaf(s, proto[16384 + cell], tp1);
            tp2 = fmaf(s, proto[32768 + cell], tp2);
            tp3 = fmaf(s, proto[49152 + cell], tp3);
        }
        tp0 = wave_sum(tp0); tp1 = wave_sum(tp1); tp2 = wave_sum(tp2); tp3 = wave_sum(tp3);
        if (lane == 0) { smem[wave][0] = tp0; smem[wave][1] = tp1; smem[wave][2] = tp2; smem[wave][3] = tp3; }
        __syncthreads();
        if (t < 4)
            Tpart[(bid << 2) + t] = smem[0][t] + smem[1][t] + smem[2][t] + smem[3][t];
        return;
    }

    // ---- softplus: 2 m's per block, proto read once per block ----
    const int m0 = (bid - 512) * 2;          // m0, m0+1
    const int ra = pos_idx[m0 * 3 + 0], ha = pos_idx[m0 * 3 + 1], wa = pos_idx[m0 * 3 + 2];
    const int rb = pos_idx[m0 * 3 + 3], hb = pos_idx[m0 * 3 + 4], wb = pos_idx[m0 * 3 + 5];
    const int offa = (ra << 2) * 4096 + ha * 64 + wa;
    const int offb = (rb << 2) * 4096 + hb * 64 + wb;
    const float a0 = map_coef[offa], a1 = map_coef[offa + 4096];
    const float a2 = map_coef[offa + 8192], a3 = map_coef[offa + 12288];
    const float b0 = map_coef[offb], b1 = map_coef[offb + 4096];
    const float b2 = map_coef[offb + 8192], b3 = map_coef[offb + 12288];
    float spa = 0.f, spb = 0.f;
#pragma unroll 4
    for (int i = 0; i < 16; ++i) {
        int f = (t + (i << 8)) << 2;
        float4 p0 = *reinterpret_cast<const float4*>(proto + f);
        float4 p1 = *reinterpret_cast<const float4*>(proto + 16384 + f);
        float4 p2 = *reinterpret_cast<const float4*>(proto + 32768 + f);
        float4 p3 = *reinterpret_cast<const float4*>(proto + 49152 + f);
        float L;
        L = fmaf(a3, p3.x, fmaf(a2, p2.x, fmaf(a1, p1.x, a0 * p0.x))); spa += softplusf(L);
        L = fmaf(a3, p3.y, fmaf(a2, p2.y, fmaf(a1, p1.y, a0 * p0.y))); spa += softplusf(L);
        L = fmaf(a3, p3.z, fmaf(a2, p2.z, fmaf(a1, p1.z, a0 * p0.z))); spa += softplusf(L);
        L = fmaf(a3, p3.w, fmaf(a2, p2.w, fmaf(a1, p1.w, a0 * p0.w))); spa += softplusf(L);
        L = fmaf(b3, p3.x, fmaf(b2, p2.x, fmaf(b1, p1.x, b0 * p0.x))); spb += softplusf(L);
        L = fmaf(b3, p3.y, fmaf(b2, p2.y, fmaf(b1, p1.y, b0 * p0.y))); spb += softplusf(L);
        L = fmaf(b3, p3.z, fmaf(b2, p2.z, fmaf(b1, p1.z, b0 * p0.z))); spb += softplusf(L);
        L = fmaf(b3, p3.w, fmaf(b2, p2.w, fmaf(b1, p1.w, b0 * p0.w))); spb += softplusf(L);
    }
    spa = wave_sum(spa); spb = wave_sum(spb);
    if (lane == 0) { smem[wave][0] = spa; smem[wave][1] = spb; }
    __syncthreads();
    if (t < 2)
        SP[m0 + t] = smem[0][t] + smem[1][t] + smem[2][t] + smem[3][t];
}

__global__ void __launch_bounds__(256)
k_final(const float* __restrict__ map_class,
        const float* __restrict__ map_box,
        const float* __restrict__ map_coef,
        const float* __restrict__ anchor_center,
        const float* __restrict__ anchor_box,
        const float* __restrict__ gt_boxes,
        const int* __restrict__ pos_idx,
        const int* __restrict__ gt_idx,
        const int* __restrict__ neg_idx,
        const float* __restrict__ Tpart,
        const float* __restrict__ SP,
        float* __restrict__ out) {
    const int t = threadIdx.x;
    const int wave = t >> 6, lane = t & 63;
    __shared__ float sT[128];
    __shared__ float smem[4];

    if (t < 128) {                       // T[g][p] = sum of 16 chunk partials
        const int g = t >> 2, p = t & 3;
        float s = 0.f;
#pragma unroll
        for (int chunk = 0; chunk < 16; ++chunk)
            s += Tpart[(((g << 4) + chunk) << 2) + p];
        sT[t] = s;
    }
    __syncthreads();

    // per-thread m = t: cls + loc + mask combine
    float contrib;
    {
        const int r = pos_idx[t * 3 + 0], h = pos_idx[t * 3 + 1], w = pos_idx[t * 3 + 2];
        const int hw = h * 64 + w;
        float sum = softplusf(-map_class[r * 4096 + hw]);
        for (int j = 0; j < 3; ++j) {
            int n = t + (j << 8);
            int rn = neg_idx[n * 3 + 0], hn = neg_idx[n * 3 + 1], wn = neg_idx[n * 3 + 2];
            sum += softplusf(map_class[rn * 4096 + hn * 64 + wn]);
        }
        const float ach = anchor_center[hw];
        const float acw = anchor_center[4096 + hw];
        const float ah = anchor_box[r * 2 + 0];
        const float aw = anchor_box[r * 2 + 1];
        const int g = gt_idx[t];
        const float g0 = gt_boxes[g * 4 + 0], g1 = gt_boxes[g * 4 + 1];
        const float g2 = gt_boxes[g * 4 + 2], g3 = gt_boxes[g * 4 + 3];
        float tgt[4] = { (g0 - ach) / ah, (g1 - acw) / aw, log10f(g2 / ah), log10f(g3 / aw) };
#pragma unroll
        for (int j = 0; j < 4; ++j) {
            float d = map_box[(r * 4 + j) * 4096 + hw] - tgt[j];
            float a = fabsf(d);
            sum += (a < 1.0f) ? 0.5f * d * d : a - 0.5f;
        }
        const int off = (r << 2) * 4096 + hw;
        const float c0 = map_coef[off];
        const float c1 = map_coef[off + 4096];
        const float c2 = map_coef[off + 8192];
        const float c3 = map_coef[off + 12288];
        const float dotT = fmaf(c3, sT[g * 4 + 3], fmaf(c2, sT[g * 4 + 2],
                           fmaf(c1, sT[g * 4 + 1], c0 * sT[g * 4 + 0])));
        contrib = sum + (16.f * SP[t] - dotT) * INV_TOTAL;
    }
    contrib = wave_sum(contrib);
    if (lane == 0) smem[wave] = contrib;
    __syncthreads();
    if (t == 0)
        out[0] = smem[0] + smem[1] + smem[2] + smem[3];
}

extern "C" void kernel_launch(void* const* d_in, const int* in_sizes, int n_in,
                              void* d_out, int out_size, void* d_ws, size_t ws_size,
                              hipStream_t stream) {
    const float* proto         = (const float*)d_in[0];
    const float* map_class     = (const float*)d_in[1];
    const float* map_box       = (const float*)d_in[2];
    const float* map_coef      = (const float*)d_in[3];
    const float* anchor_center = (const float*)d_in[4];
    const float* anchor_box    = (const float*)d_in[5];
    const float* gt_boxes      = (const float*)d_in[6];
    const float* gt_masks      = (const float*)d_in[7];
    const int*   pos_idx       = (const int*)d_in[8];
    const int*   gt_idx        = (const int*)d_in[9];
    const int*   neg_idx       = (const int*)d_in[10];

    float* Tpart = (float*)d_ws;          // 2048 floats
    float* SP    = Tpart + 2048;          // 256 floats
    float* out   = (float*)d_out;

    k_workers<<<640, 256, 0, stream>>>(proto, map_coef, gt_masks, pos_idx, Tpart, SP);
    k_final<<<1, 256, 0, stream>>>(map_class, map_box, map_coef, anchor_center,
                                   anchor_box, gt_boxes, pos_idx, gt_idx, neg_idx,
                                   Tpart, SP, out);
}

// Round 7
// 103.582 us; speedup vs baseline: 1.0841x; 1.0841x over previous
//
#include <hip/hip_runtime.h>
#include <math.h>

// Problem: M=256 positives, 3M=768 negatives, NUM_GT=32,
// proto (4,128,128), maps (*,64,64), gt_masks (32,512,512).
//
// Mask-loss restructure (verified exact rounds 1-4):
//   mean(bce_m) = (1/512^2) * [ 16 * sum_{hw in 128^2} softplus(L_m[hw])
//                               - dot(coef_m, T[gt_m]) ]
//   T[g,p] = sum_{512^2} gt_masks[g] * proto[p, y/4, x/4]
//
// Structure (round 4, proven best = 103.2 us): 2 dispatches, ZERO
// device-scope atomics.
// Lessons:
//  - rounds 2-3: far-atomics funneled to one line across 8 XCDs serialize
//    (~25 us for ~1k RMWs) — publish via disjoint plain stores + dependent
//    kernel instead.
//  - round 6: __builtin_nontemporal_load on the gt_masks stream REGRESSED
//    (+9 us): nt bits bypass L2/L3 retention, but L3 was absorbing ~half
//    the 33.5 MB stream (FETCH_SIZE 18 MB in round 3). Keep default
//    cache policy. Also keep 1 m per softplus block (short tail).
//
//   k_workers (768 blocks): [0,512) tmat slab partials -> Tpart;
//                           [512,768) per-m softplus -> SP.
//   k_final   (1 block): reduce Tpart, cls+loc+combine, write scalar.

#define INV_TOTAL (1.0f / (262144.0f * 256.0f))

__device__ __forceinline__ float softplusf(float x) {
    return fmaxf(x, 0.0f) + __logf(1.0f + __expf(-fabsf(x)));
}

__device__ __forceinline__ float wave_sum(float v) {
    v += __shfl_down(v, 32);
    v += __shfl_down(v, 16);
    v += __shfl_down(v, 8);
    v += __shfl_down(v, 4);
    v += __shfl_down(v, 2);
    v += __shfl_down(v, 1);
    return v;
}

__global__ void __launch_bounds__(256)
k_workers(const float* __restrict__ proto,
          const float* __restrict__ map_coef,
          const float* __restrict__ gt_masks,
          const int* __restrict__ pos_idx,
          float* __restrict__ Tpart,   // [512*4] slab partials, slot = bid
          float* __restrict__ SP) {    // [256] per-m softplus sums
    const int bid = blockIdx.x;
    const int t = threadIdx.x;
    const int wave = t >> 6, lane = t & 63;
    __shared__ float smem[4][4];

    if (bid < 512) {
        // ---- tmat: partial T over a 32-row slab of gt_masks[g] ----
        const int g = bid >> 4, chunk = bid & 15;
        const float* mask = gt_masks + (size_t)g * (512 * 512);
        float tp0 = 0.f, tp1 = 0.f, tp2 = 0.f, tp3 = 0.f;
#pragma unroll 4
        for (int i = 0; i < 16; ++i) {
            int f = t + (i << 8);            // 0..4095 float4s in 32x512 slab
            int yl = f >> 7;                 // 128 float4 per row
            int k  = f & 127;
            int y  = (chunk << 5) + yl;
            float4 mv = *reinterpret_cast<const float4*>(mask + y * 512 + (k << 2));
            float s = (mv.x + mv.y) + (mv.z + mv.w);
            int cell = ((y >> 2) << 7) + k;
            tp0 = fmaf(s, proto[cell],         tp0);
            tp1 = fmaf(s, proto[16384 + cell], tp1);
            tp2 = fmaf(s, proto[32768 + cell], tp2);
            tp3 = fmaf(s, proto[49152 + cell], tp3);
        }
        tp0 = wave_sum(tp0); tp1 = wave_sum(tp1); tp2 = wave_sum(tp2); tp3 = wave_sum(tp3);
        if (lane == 0) { smem[wave][0] = tp0; smem[wave][1] = tp1; smem[wave][2] = tp2; smem[wave][3] = tp3; }
        __syncthreads();
        if (t < 4)
            Tpart[(bid << 2) + t] = smem[0][t] + smem[1][t] + smem[2][t] + smem[3][t];
        return;
    }

    // ---- per-m mask softplus over L2/L3-resident proto ----
    const int m = bid - 512;
    const int r = pos_idx[m * 3 + 0], h = pos_idx[m * 3 + 1], w = pos_idx[m * 3 + 2];
    const int off = (r << 2) * 4096 + h * 64 + w;
    const float c0 = map_coef[off];
    const float c1 = map_coef[off + 4096];
    const float c2 = map_coef[off + 8192];
    const float c3 = map_coef[off + 12288];
    float sp = 0.f;
#pragma unroll 4
    for (int i = 0; i < 16; ++i) {
        int f = (t + (i << 8)) << 2;
        float4 p0 = *reinterpret_cast<const float4*>(proto + f);
        float4 p1 = *reinterpret_cast<const float4*>(proto + 16384 + f);
        float4 p2 = *reinterpret_cast<const float4*>(proto + 32768 + f);
        float4 p3 = *reinterpret_cast<const float4*>(proto + 49152 + f);
        float L;
        L = fmaf(c3, p3.x, fmaf(c2, p2.x, fmaf(c1, p1.x, c0 * p0.x))); sp += softplusf(L);
        L = fmaf(c3, p3.y, fmaf(c2, p2.y, fmaf(c1, p1.y, c0 * p0.y))); sp += softplusf(L);
        L = fmaf(c3, p3.z, fmaf(c2, p2.z, fmaf(c1, p1.z, c0 * p0.z))); sp += softplusf(L);
        L = fmaf(c3, p3.w, fmaf(c2, p2.w, fmaf(c1, p1.w, c0 * p0.w))); sp += softplusf(L);
    }
    sp = wave_sum(sp);
    if (lane == 0) smem[wave][0] = sp;
    __syncthreads();
    if (t == 0)
        SP[m] = smem[0][0] + smem[1][0] + smem[2][0] + smem[3][0];
}

__global__ void __launch_bounds__(256)
k_final(const float* __restrict__ map_class,
        const float* __restrict__ map_box,
        const float* __restrict__ map_coef,
        const float* __restrict__ anchor_center,
        const float* __restrict__ anchor_box,
        const float* __restrict__ gt_boxes,
        const int* __restrict__ pos_idx,
        const int* __restrict__ gt_idx,
        const int* __restrict__ neg_idx,
        const float* __restrict__ Tpart,
        const float* __restrict__ SP,
        float* __restrict__ out) {
    const int t = threadIdx.x;
    const int wave = t >> 6, lane = t & 63;
    __shared__ float sT[128];
    __shared__ float smem[4];

    if (t < 128) {                       // T[g][p] = sum of 16 chunk partials
        const int g = t >> 2, p = t & 3;
        float s = 0.f;
#pragma unroll
        for (int chunk = 0; chunk < 16; ++chunk)
            s += Tpart[(((g << 4) + chunk) << 2) + p];
        sT[t] = s;
    }
    __syncthreads();

    // per-thread m = t: cls + loc + mask combine
    float contrib;
    {
        const int r = pos_idx[t * 3 + 0], h = pos_idx[t * 3 + 1], w = pos_idx[t * 3 + 2];
        const int hw = h * 64 + w;
        float sum = softplusf(-map_class[r * 4096 + hw]);
        for (int j = 0; j < 3; ++j) {
            int n = t + (j << 8);
            int rn = neg_idx[n * 3 + 0], hn = neg_idx[n * 3 + 1], wn = neg_idx[n * 3 + 2];
            sum += softplusf(map_class[rn * 4096 + hn * 64 + wn]);
        }
        const float ach = anchor_center[hw];
        const float acw = anchor_center[4096 + hw];
        const float ah = anchor_box[r * 2 + 0];
        const float aw = anchor_box[r * 2 + 1];
        const int g = gt_idx[t];
        const float g0 = gt_boxes[g * 4 + 0], g1 = gt_boxes[g * 4 + 1];
        const float g2 = gt_boxes[g * 4 + 2], g3 = gt_boxes[g * 4 + 3];
        float tgt[4] = { (g0 - ach) / ah, (g1 - acw) / aw, log10f(g2 / ah), log10f(g3 / aw) };
#pragma unroll
        for (int j = 0; j < 4; ++j) {
            float d = map_box[(r * 4 + j) * 4096 + hw] - tgt[j];
            float a = fabsf(d);
            sum += (a < 1.0f) ? 0.5f * d * d : a - 0.5f;
        }
        const int off = (r << 2) * 4096 + hw;
        const float c0 = map_coef[off];
        const float c1 = map_coef[off + 4096];
        const float c2 = map_coef[off + 8192];
        const float c3 = map_coef[off + 12288];
        const float dotT = fmaf(c3, sT[g * 4 + 3], fmaf(c2, sT[g * 4 + 2],
                           fmaf(c1, sT[g * 4 + 1], c0 * sT[g * 4 + 0])));
        contrib = sum + (16.f * SP[t] - dotT) * INV_TOTAL;
    }
    contrib = wave_sum(contrib);
    if (lane == 0) smem[wave] = contrib;
    __syncthreads();
    if (t == 0)
        out[0] = smem[0] + smem[1] + smem[2] + smem[3];
}

extern "C" void kernel_launch(void* const* d_in, const int* in_sizes, int n_in,
                              void* d_out, int out_size, void* d_ws, size_t ws_size,
                              hipStream_t stream) {
    const float* proto         = (const float*)d_in[0];
    const float* map_class     = (const float*)d_in[1];
    const float* map_box       = (const float*)d_in[2];
    const float* map_coef      = (const float*)d_in[3];
    const float* anchor_center = (const float*)d_in[4];
    const float* anchor_box    = (const float*)d_in[5];
    const float* gt_boxes      = (const float*)d_in[6];
    const float* gt_masks      = (const float*)d_in[7];
    const int*   pos_idx       = (const int*)d_in[8];
    const int*   gt_idx        = (const int*)d_in[9];
    const int*   neg_idx       = (const int*)d_in[10];

    float* Tpart = (float*)d_ws;          // 2048 floats
    float* SP    = Tpart + 2048;          // 256 floats
    float* out   = (float*)d_out;

    k_workers<<<768, 256, 0, stream>>>(proto, map_coef, gt_masks, pos_idx, Tpart, SP);
    k_final<<<1, 256, 0, stream>>>(map_class, map_box, map_coef, anchor_center,
                                   anchor_box, gt_boxes, pos_idx, gt_idx, neg_idx,
                                   Tpart, SP, out);
}

// Round 8
// 103.037 us; speedup vs baseline: 1.0898x; 1.0053x over previous
//
#include <hip/hip_runtime.h>
#include <math.h>

// Problem: M=256 positives, 3M=768 negatives, NUM_GT=32,
// proto (4,128,128), maps (*,64,64), gt_masks (32,512,512).
//
// Mask-loss restructure (verified exact rounds 1-7):
//   mean(bce_m) = (1/512^2) * [ 16 * sum_{hw in 128^2} softplus(L_m[hw])
//                               - dot(coef_m, T[gt_m]) ]
//   T[g,p] = sum_{512^2} gt_masks[g] * proto[p, y/4, x/4]
//
// Structure: 2 dispatches, ZERO device-scope atomics.
// Lessons:
//  - R2-3: far-atomics funneled through one line across 8 XCDs serialize
//    (~25 us) — publish via disjoint plain stores + dependent kernel.
//  - R6: nontemporal loads on the gt_masks stream regressed (+9 us): L3 was
//    absorbing ~half the 33.5 MB stream; keep default cache policy.
//  - R8: k_final made a pure dense combine — cls/loc moved to worker block
//    768 (runs in tmat's shadow), coefs stored densely by softplus blocks.
//
//   k_workers (769 blocks): [0,512) tmat slab partials -> Tpart;
//                           [512,768) per-m softplus -> SP, coef -> C4;
//                           768: cls+loc -> CL.
//   k_final   (1 block): reduce Tpart, dense combine, write scalar.

#define INV_TOTAL (1.0f / (262144.0f * 256.0f))

__device__ __forceinline__ float softplusf(float x) {
    return fmaxf(x, 0.0f) + __logf(1.0f + __expf(-fabsf(x)));
}

__device__ __forceinline__ float wave_sum(float v) {
    v += __shfl_down(v, 32);
    v += __shfl_down(v, 16);
    v += __shfl_down(v, 8);
    v += __shfl_down(v, 4);
    v += __shfl_down(v, 2);
    v += __shfl_down(v, 1);
    return v;
}

__global__ void __launch_bounds__(256)
k_workers(const float* __restrict__ proto,
          const float* __restrict__ map_coef,
          const float* __restrict__ map_class,
          const float* __restrict__ map_box,
          const float* __restrict__ anchor_center,
          const float* __restrict__ anchor_box,
          const float* __restrict__ gt_boxes,
          const float* __restrict__ gt_masks,
          const int* __restrict__ pos_idx,
          const int* __restrict__ gt_idx,
          const int* __restrict__ neg_idx,
          float* __restrict__ Tpart,   // [512*4] slab partials, slot = bid
          float* __restrict__ SP,      // [256] per-m softplus sums
          float* __restrict__ C4,      // [256*4] per-m coefs, dense
          float* __restrict__ CL) {    // [1] cls+loc scalar
    const int bid = blockIdx.x;
    const int t = threadIdx.x;
    const int wave = t >> 6, lane = t & 63;
    __shared__ float smem[4][4];

    if (bid < 512) {
        // ---- tmat: partial T over a 32-row slab of gt_masks[g] ----
        const int g = bid >> 4, chunk = bid & 15;
        const float* mask = gt_masks + (size_t)g * (512 * 512);
        float tp0 = 0.f, tp1 = 0.f, tp2 = 0.f, tp3 = 0.f;
#pragma unroll 4
        for (int i = 0; i < 16; ++i) {
            int f = t + (i << 8);            // 0..4095 float4s in 32x512 slab
            int yl = f >> 7;                 // 128 float4 per row
            int k  = f & 127;
            int y  = (chunk << 5) + yl;
            float4 mv = *reinterpret_cast<const float4*>(mask + y * 512 + (k << 2));
            float s = (mv.x + mv.y) + (mv.z + mv.w);
            int cell = ((y >> 2) << 7) + k;
            tp0 = fmaf(s, proto[cell],         tp0);
            tp1 = fmaf(s, proto[16384 + cell], tp1);
            tp2 = fmaf(s, proto[32768 + cell], tp2);
            tp3 = fmaf(s, proto[49152 + cell], tp3);
        }
        tp0 = wave_sum(tp0); tp1 = wave_sum(tp1); tp2 = wave_sum(tp2); tp3 = wave_sum(tp3);
        if (lane == 0) { smem[wave][0] = tp0; smem[wave][1] = tp1; smem[wave][2] = tp2; smem[wave][3] = tp3; }
        __syncthreads();
        if (t < 4)
            Tpart[(bid << 2) + t] = smem[0][t] + smem[1][t] + smem[2][t] + smem[3][t];
        return;
    }

    if (bid < 768) {
        // ---- per-m mask softplus over L2/L3-resident proto ----
        const int m = bid - 512;
        const int r = pos_idx[m * 3 + 0], h = pos_idx[m * 3 + 1], w = pos_idx[m * 3 + 2];
        const int off = (r << 2) * 4096 + h * 64 + w;
        const float c0 = map_coef[off];
        const float c1 = map_coef[off + 4096];
        const float c2 = map_coef[off + 8192];
        const float c3 = map_coef[off + 12288];
        float sp = 0.f;
#pragma unroll 4
        for (int i = 0; i < 16; ++i) {
            int f = (t + (i << 8)) << 2;
            float4 p0 = *reinterpret_cast<const float4*>(proto + f);
            float4 p1 = *reinterpret_cast<const float4*>(proto + 16384 + f);
            float4 p2 = *reinterpret_cast<const float4*>(proto + 32768 + f);
            float4 p3 = *reinterpret_cast<const float4*>(proto + 49152 + f);
            float L;
            L = fmaf(c3, p3.x, fmaf(c2, p2.x, fmaf(c1, p1.x, c0 * p0.x))); sp += softplusf(L);
            L = fmaf(c3, p3.y, fmaf(c2, p2.y, fmaf(c1, p1.y, c0 * p0.y))); sp += softplusf(L);
            L = fmaf(c3, p3.z, fmaf(c2, p2.z, fmaf(c1, p1.z, c0 * p0.z))); sp += softplusf(L);
            L = fmaf(c3, p3.w, fmaf(c2, p2.w, fmaf(c1, p1.w, c0 * p0.w))); sp += softplusf(L);
        }
        sp = wave_sum(sp);
        if (lane == 0) smem[wave][0] = sp;
        __syncthreads();
        if (t == 0) {
            SP[m] = smem[0][0] + smem[1][0] + smem[2][0] + smem[3][0];
            C4[(m << 2) + 0] = c0; C4[(m << 2) + 1] = c1;
            C4[(m << 2) + 2] = c2; C4[(m << 2) + 3] = c3;
        }
        return;
    }

    // ---- bid == 768: cls + loc (no worker dependency; runs in tmat shadow) ----
    float sum;
    {
        const int r = pos_idx[t * 3 + 0], h = pos_idx[t * 3 + 1], w = pos_idx[t * 3 + 2];
        const int hw = h * 64 + w;
        sum = softplusf(-map_class[r * 4096 + hw]);
        for (int j = 0; j < 3; ++j) {
            int n = t + (j << 8);
            int rn = neg_idx[n * 3 + 0], hn = neg_idx[n * 3 + 1], wn = neg_idx[n * 3 + 2];
            sum += softplusf(map_class[rn * 4096 + hn * 64 + wn]);
        }
        const float ach = anchor_center[hw];
        const float acw = anchor_center[4096 + hw];
        const float ah = anchor_box[r * 2 + 0];
        const float aw = anchor_box[r * 2 + 1];
        const int g = gt_idx[t];
        const float g0 = gt_boxes[g * 4 + 0], g1 = gt_boxes[g * 4 + 1];
        const float g2 = gt_boxes[g * 4 + 2], g3 = gt_boxes[g * 4 + 3];
        float tgt[4] = { (g0 - ach) / ah, (g1 - acw) / aw, log10f(g2 / ah), log10f(g3 / aw) };
#pragma unroll
        for (int j = 0; j < 4; ++j) {
            float d = map_box[(r * 4 + j) * 4096 + hw] - tgt[j];
            float a = fabsf(d);
            sum += (a < 1.0f) ? 0.5f * d * d : a - 0.5f;
        }
    }
    sum = wave_sum(sum);
    if (lane == 0) smem[wave][0] = sum;
    __syncthreads();
    if (t == 0)
        CL[0] = smem[0][0] + smem[1][0] + smem[2][0] + smem[3][0];
}

__global__ void __launch_bounds__(256)
k_final(const int* __restrict__ gt_idx,
        const float* __restrict__ Tpart,
        const float* __restrict__ SP,
        const float* __restrict__ C4,
        const float* __restrict__ CL,
        float* __restrict__ out) {
    const int t = threadIdx.x;
    const int wave = t >> 6, lane = t & 63;
    __shared__ float sT[128];
    __shared__ float smem[4];

    if (t < 128) {                       // T[g][p] = sum of 16 chunk partials
        const int g = t >> 2, p = t & 3;
        float s = 0.f;
#pragma unroll
        for (int chunk = 0; chunk < 16; ++chunk)
            s += Tpart[(((g << 4) + chunk) << 2) + p];
        sT[t] = s;
    }
    // dense per-m loads (issue before barrier)
    const int g = gt_idx[t];
    const float spm = SP[t];
    const float4 c = *reinterpret_cast<const float4*>(C4 + (t << 2));
    __syncthreads();

    const float dotT = fmaf(c.w, sT[(g << 2) + 3], fmaf(c.z, sT[(g << 2) + 2],
                       fmaf(c.y, sT[(g << 2) + 1], c.x * sT[(g << 2) + 0])));
    float contrib = (16.f * spm - dotT) * INV_TOTAL;
    contrib = wave_sum(contrib);
    if (lane == 0) smem[wave] = contrib;
    __syncthreads();
    if (t == 0)
        out[0] = CL[0] + smem[0] + smem[1] + smem[2] + smem[3];
}

extern "C" void kernel_launch(void* const* d_in, const int* in_sizes, int n_in,
                              void* d_out, int out_size, void* d_ws, size_t ws_size,
                              hipStream_t stream) {
    const float* proto         = (const float*)d_in[0];
    const float* map_class     = (const float*)d_in[1];
    const float* map_box       = (const float*)d_in[2];
    const float* map_coef      = (const float*)d_in[3];
    const float* anchor_center = (const float*)d_in[4];
    const float* anchor_box    = (const float*)d_in[5];
    const float* gt_boxes      = (const float*)d_in[6];
    const float* gt_masks      = (const float*)d_in[7];
    const int*   pos_idx       = (const int*)d_in[8];
    const int*   gt_idx        = (const int*)d_in[9];
    const int*   neg_idx       = (const int*)d_in[10];

    float* Tpart = (float*)d_ws;          // 2048 floats
    float* SP    = Tpart + 2048;          // 256 floats
    float* C4    = SP + 256;              // 1024 floats
    float* CL    = C4 + 1024;             // 1 float
    float* out   = (float*)d_out;

    k_workers<<<769, 256, 0, stream>>>(proto, map_coef, map_class, map_box,
                                       anchor_center, anchor_box, gt_boxes, gt_masks,
                                       pos_idx, gt_idx, neg_idx,
                                       Tpart, SP, C4, CL);
    k_final<<<1, 256, 0, stream>>>(gt_idx, Tpart, SP, C4, CL, out);
}